// Round 1
// baseline (402.242 us; speedup 1.0000x reference)
//
#include <hip/hip_runtime.h>

#define DDIM 128

__global__ void init_ws_kernel(float* __restrict__ seg, unsigned* __restrict__ cnt, int C) {
    int i = blockIdx.x * blockDim.x + threadIdx.x;
    if (i < C) { seg[i] = 0.0f; cnt[i] = 0u; }
}

// One 16-lane group per sample; 4 samples per wave per iteration.
__global__ __launch_bounds__(256) void dist_kernel(
    const float* __restrict__ x, const float* __restrict__ anchors,
    const int* __restrict__ y, float* __restrict__ seg,
    unsigned* __restrict__ cnt, int n)
{
    const int tid  = blockIdx.x * blockDim.x + threadIdx.x;
    const int wave = tid >> 6;
    const int lane = threadIdx.x & 63;
    const int g    = lane >> 4;   // sample slot within wave (0..3)
    const int q    = lane & 15;   // lane within 16-lane group
    const long long totalWaves = (long long)(gridDim.x * blockDim.x) >> 6;

    for (long long base = (long long)wave * 4; base < n; base += totalWaves * 4) {
        const long long i = base + g;
        float acc = 0.0f;
        int label = 0;
        if (i < n) {
            label = y[i];
            const float4* xp = (const float4*)(x + i * DDIM + q * 8);
            const float4* ap = (const float4*)(anchors + (long long)label * DDIM + q * 8);
            float4 x0 = xp[0], x1 = xp[1];
            float4 a0 = ap[0], a1 = ap[1];
            float d;
            d = x0.x - a0.x; acc = fmaf(d, d, acc);
            d = x0.y - a0.y; acc = fmaf(d, d, acc);
            d = x0.z - a0.z; acc = fmaf(d, d, acc);
            d = x0.w - a0.w; acc = fmaf(d, d, acc);
            d = x1.x - a1.x; acc = fmaf(d, d, acc);
            d = x1.y - a1.y; acc = fmaf(d, d, acc);
            d = x1.z - a1.z; acc = fmaf(d, d, acc);
            d = x1.w - a1.w; acc = fmaf(d, d, acc);
        }
        // reduce across the 16-lane group (xor offsets < 16 stay in-group)
        #pragma unroll
        for (int off = 1; off < 16; off <<= 1)
            acc += __shfl_xor(acc, off);
        if (q == 0 && i < n) {
            atomicAdd(&seg[label], acc);
            atomicAdd(&cnt[label], 1u);
        }
    }
}

__global__ __launch_bounds__(1024) void finalize_kernel(
    const float* __restrict__ seg, const unsigned* __restrict__ cnt,
    float* __restrict__ out, int C)
{
    __shared__ float red[1024];
    const int t = threadIdx.x;
    float v = 0.0f;
    for (int c = t; c < C; c += 1024) {
        unsigned k = cnt[c];
        if (k > 0u) {
            float fk = (float)k;
            v += seg[c] / (fk * fk);
        }
    }
    red[t] = v;
    __syncthreads();
    #pragma unroll
    for (int s = 512; s > 0; s >>= 1) {
        if (t < s) red[t] += red[t + s];
        __syncthreads();
    }
    if (t == 0) out[0] = red[0];
}

extern "C" void kernel_launch(void* const* d_in, const int* in_sizes, int n_in,
                              void* d_out, int out_size, void* d_ws, size_t ws_size,
                              hipStream_t stream) {
    const float* x       = (const float*)d_in[0];
    const float* anchors = (const float*)d_in[1];
    const int*   y       = (const int*)d_in[2];
    float*       out     = (float*)d_out;

    const int n = in_sizes[2];          // N samples
    const int C = in_sizes[1] / DDIM;   // number of classes

    // ws layout: seg[C] floats, then cnt[C] uints (256B-aligned)
    float*    seg = (float*)d_ws;
    size_t    segBytes = ((size_t)C * sizeof(float) + 255) & ~(size_t)255;
    unsigned* cnt = (unsigned*)((char*)d_ws + segBytes);

    init_ws_kernel<<<(C + 255) / 256, 256, 0, stream>>>(seg, cnt, C);

    const int blocks = 2048;            // 8 blocks/CU worth of waves, grid-stride
    dist_kernel<<<blocks, 256, 0, stream>>>(x, anchors, y, seg, cnt, n);

    finalize_kernel<<<1, 1024, 0, stream>>>(seg, cnt, out, C);
}

// Round 2
// 141.909 us; speedup vs baseline: 2.8345x; 2.8345x over previous
//
#include <hip/hip_runtime.h>

#define DDIM 128

// Stage A: stream x, compute per-sample ||x - a_y||^2 via 16-lane groups,
// accumulate per-class sums/counts in LDS, flush per-block partials (no global atomics).
__global__ __launch_bounds__(256) void dist_kernel(
    const float* __restrict__ x, const float* __restrict__ anchors,
    const int* __restrict__ y,
    float* __restrict__ pseg, unsigned* __restrict__ pcnt,
    int n, int C)
{
    extern __shared__ char smem[];
    float*    segL = (float*)smem;
    unsigned* cntL = (unsigned*)(smem + (size_t)C * sizeof(float));

    for (int c = threadIdx.x; c < C; c += blockDim.x) { segL[c] = 0.0f; cntL[c] = 0u; }
    __syncthreads();

    const int tid  = blockIdx.x * blockDim.x + threadIdx.x;
    const int wave = tid >> 6;
    const int lane = threadIdx.x & 63;
    const int g    = lane >> 4;   // sample slot within wave (0..3)
    const int q    = lane & 15;   // lane within 16-lane group
    const long long totalWaves = ((long long)gridDim.x * blockDim.x) >> 6;

    for (long long base = (long long)wave * 4; base < n; base += totalWaves * 4) {
        const long long i = base + g;
        float acc = 0.0f;
        int label = 0;
        if (i < n) {
            label = y[i];
            const float4* xp = (const float4*)(x + i * DDIM + q * 8);
            const float4* ap = (const float4*)(anchors + (long long)label * DDIM + q * 8);
            float4 x0 = xp[0], x1 = xp[1];
            float4 a0 = ap[0], a1 = ap[1];
            float d;
            d = x0.x - a0.x; acc = fmaf(d, d, acc);
            d = x0.y - a0.y; acc = fmaf(d, d, acc);
            d = x0.z - a0.z; acc = fmaf(d, d, acc);
            d = x0.w - a0.w; acc = fmaf(d, d, acc);
            d = x1.x - a1.x; acc = fmaf(d, d, acc);
            d = x1.y - a1.y; acc = fmaf(d, d, acc);
            d = x1.z - a1.z; acc = fmaf(d, d, acc);
            d = x1.w - a1.w; acc = fmaf(d, d, acc);
        }
        #pragma unroll
        for (int off = 1; off < 16; off <<= 1)
            acc += __shfl_xor(acc, off);
        if (q == 0 && i < n) {
            atomicAdd(&segL[label], acc);   // LDS atomic (ds_add_f32)
            atomicAdd(&cntL[label], 1u);    // LDS atomic
        }
    }
    __syncthreads();

    float*    myseg = pseg + (size_t)blockIdx.x * C;
    unsigned* mycnt = pcnt + (size_t)blockIdx.x * C;
    for (int c = threadIdx.x; c < C; c += blockDim.x) {
        myseg[c] = segL[c];
        mycnt[c] = cntL[c];
    }
}

// Stage B: one block per class; sum partials over B blocks, write per_class[c].
__global__ __launch_bounds__(256) void reduce_kernel(
    const float* __restrict__ pseg, const unsigned* __restrict__ pcnt,
    float* __restrict__ per_class, int B, int C)
{
    const int c = blockIdx.x;
    float s = 0.0f, k = 0.0f;
    for (int b = threadIdx.x; b < B; b += blockDim.x) {
        s += pseg[(size_t)b * C + c];
        k += (float)pcnt[(size_t)b * C + c];
    }
    #pragma unroll
    for (int off = 32; off > 0; off >>= 1) {
        s += __shfl_down(s, off);
        k += __shfl_down(k, off);
    }
    __shared__ float sh_s[4], sh_k[4];
    const int w = threadIdx.x >> 6;
    if ((threadIdx.x & 63) == 0) { sh_s[w] = s; sh_k[w] = k; }
    __syncthreads();
    if (threadIdx.x == 0) {
        float S = sh_s[0] + sh_s[1] + sh_s[2] + sh_s[3];
        float K = sh_k[0] + sh_k[1] + sh_k[2] + sh_k[3];
        per_class[c] = (K > 0.0f) ? S / (K * K) : 0.0f;
    }
}

// Stage C: single block reduces per_class[C] into out[0].
__global__ __launch_bounds__(1024) void finalize_kernel(
    const float* __restrict__ per_class, float* __restrict__ out, int C)
{
    __shared__ float red[1024];
    const int t = threadIdx.x;
    float v = 0.0f;
    for (int c = t; c < C; c += 1024) v += per_class[c];
    red[t] = v;
    __syncthreads();
    #pragma unroll
    for (int s = 512; s > 0; s >>= 1) {
        if (t < s) red[t] += red[t + s];
        __syncthreads();
    }
    if (t == 0) out[0] = red[0];
}

extern "C" void kernel_launch(void* const* d_in, const int* in_sizes, int n_in,
                              void* d_out, int out_size, void* d_ws, size_t ws_size,
                              hipStream_t stream) {
    const float* x       = (const float*)d_in[0];
    const float* anchors = (const float*)d_in[1];
    const int*   y       = (const int*)d_in[2];
    float*       out     = (float*)d_out;

    const int n = in_sizes[2];          // N samples
    const int C = in_sizes[1] / DDIM;   // classes

    // Choose B (streaming blocks) limited by workspace: need B*C*8 + C*4 bytes.
    long long cap = ((long long)ws_size - (long long)C * 4) / ((long long)C * 8);
    int B = (int)(cap < 1 ? 1 : (cap > 2048 ? 2048 : cap));

    float*    pseg      = (float*)d_ws;
    unsigned* pcnt      = (unsigned*)((char*)d_ws + (size_t)B * C * sizeof(float));
    float*    per_class = (float*)((char*)d_ws + (size_t)B * C * 8);

    const size_t ldsBytes = (size_t)C * 8;  // segL + cntL
    dist_kernel<<<B, 256, ldsBytes, stream>>>(x, anchors, y, pseg, pcnt, n, C);
    reduce_kernel<<<C, 256, 0, stream>>>(pseg, pcnt, per_class, B, C);
    finalize_kernel<<<1, 1024, 0, stream>>>(per_class, out, C);
}

// Round 3
// 127.291 us; speedup vs baseline: 3.1600x; 1.1148x over previous
//
#include <hip/hip_runtime.h>

#define DDIM 128

// Stage A: stream x, compute per-sample ||x - a_y||^2 via 16-lane groups
// (2 samples per group per iteration for MLP), accumulate per-class sums/counts
// in LDS, flush per-block partials (no global atomics).
__global__ __launch_bounds__(256) void dist_kernel(
    const float* __restrict__ x, const float* __restrict__ anchors,
    const int* __restrict__ y,
    float* __restrict__ pseg, unsigned* __restrict__ pcnt,
    int n, int C)
{
    extern __shared__ char smem[];
    float*    segL = (float*)smem;
    unsigned* cntL = (unsigned*)(smem + (size_t)C * sizeof(float));

    for (int c = threadIdx.x; c < C; c += blockDim.x) { segL[c] = 0.0f; cntL[c] = 0u; }
    __syncthreads();

    const int tid  = blockIdx.x * blockDim.x + threadIdx.x;
    const int wave = tid >> 6;
    const int lane = threadIdx.x & 63;
    const int g    = lane >> 4;   // sample group within wave (0..3)
    const int q    = lane & 15;   // lane within 16-lane group
    const int totalWaves = (gridDim.x * blockDim.x) >> 6;
    const int stride = totalWaves * 8;          // 8 samples per wave per iter

    for (int base = wave * 8; base < n; base += stride) {
        const int i0 = base + g;        // sample A for this group
        const int i1 = base + g + 4;    // sample B for this group
        const bool v0 = i0 < n, v1 = i1 < n;

        int l0 = 0, l1 = 0;
        if (v0) l0 = y[i0];
        if (v1) l1 = y[i1];

        float4 xa0, xa1, xb0, xb1;
        float4 aa0, aa1, ab0, ab1;
        if (v0) {
            const float4* xp = (const float4*)(x + (size_t)i0 * DDIM + q * 8);
            xa0 = xp[0]; xa1 = xp[1];
        }
        if (v1) {
            const float4* xp = (const float4*)(x + (size_t)i1 * DDIM + q * 8);
            xb0 = xp[0]; xb1 = xp[1];
        }
        if (v0) {
            const float4* ap = (const float4*)(anchors + (size_t)l0 * DDIM + q * 8);
            aa0 = ap[0]; aa1 = ap[1];
        }
        if (v1) {
            const float4* ap = (const float4*)(anchors + (size_t)l1 * DDIM + q * 8);
            ab0 = ap[0]; ab1 = ap[1];
        }

        float acc0 = 0.0f, acc1 = 0.0f;
        if (v0) {
            float d;
            d = xa0.x - aa0.x; acc0 = fmaf(d, d, acc0);
            d = xa0.y - aa0.y; acc0 = fmaf(d, d, acc0);
            d = xa0.z - aa0.z; acc0 = fmaf(d, d, acc0);
            d = xa0.w - aa0.w; acc0 = fmaf(d, d, acc0);
            d = xa1.x - aa1.x; acc0 = fmaf(d, d, acc0);
            d = xa1.y - aa1.y; acc0 = fmaf(d, d, acc0);
            d = xa1.z - aa1.z; acc0 = fmaf(d, d, acc0);
            d = xa1.w - aa1.w; acc0 = fmaf(d, d, acc0);
        }
        if (v1) {
            float d;
            d = xb0.x - ab0.x; acc1 = fmaf(d, d, acc1);
            d = xb0.y - ab0.y; acc1 = fmaf(d, d, acc1);
            d = xb0.z - ab0.z; acc1 = fmaf(d, d, acc1);
            d = xb0.w - ab0.w; acc1 = fmaf(d, d, acc1);
            d = xb1.x - ab1.x; acc1 = fmaf(d, d, acc1);
            d = xb1.y - ab1.y; acc1 = fmaf(d, d, acc1);
            d = xb1.z - ab1.z; acc1 = fmaf(d, d, acc1);
            d = xb1.w - ab1.w; acc1 = fmaf(d, d, acc1);
        }

        #pragma unroll
        for (int off = 1; off < 16; off <<= 1) {
            acc0 += __shfl_xor(acc0, off);
            acc1 += __shfl_xor(acc1, off);
        }
        if (q == 0) {
            if (v0) { atomicAdd(&segL[l0], acc0); atomicAdd(&cntL[l0], 1u); }
            if (v1) { atomicAdd(&segL[l1], acc1); atomicAdd(&cntL[l1], 1u); }
        }
    }
    __syncthreads();

    float*    myseg = pseg + (size_t)blockIdx.x * C;
    unsigned* mycnt = pcnt + (size_t)blockIdx.x * C;
    for (int c = threadIdx.x; c < C; c += blockDim.x) {
        myseg[c] = segL[c];
        mycnt[c] = cntL[c];
    }
}

// Stage B: one block per class; sum partials over B blocks, write per_class[c].
__global__ __launch_bounds__(256) void reduce_kernel(
    const float* __restrict__ pseg, const unsigned* __restrict__ pcnt,
    float* __restrict__ per_class, int B, int C)
{
    const int c = blockIdx.x;
    float s = 0.0f, k = 0.0f;
    for (int b = threadIdx.x; b < B; b += blockDim.x) {
        s += pseg[(size_t)b * C + c];
        k += (float)pcnt[(size_t)b * C + c];
    }
    #pragma unroll
    for (int off = 32; off > 0; off >>= 1) {
        s += __shfl_down(s, off);
        k += __shfl_down(k, off);
    }
    __shared__ float sh_s[4], sh_k[4];
    const int w = threadIdx.x >> 6;
    if ((threadIdx.x & 63) == 0) { sh_s[w] = s; sh_k[w] = k; }
    __syncthreads();
    if (threadIdx.x == 0) {
        float S = sh_s[0] + sh_s[1] + sh_s[2] + sh_s[3];
        float K = sh_k[0] + sh_k[1] + sh_k[2] + sh_k[3];
        per_class[c] = (K > 0.0f) ? S / (K * K) : 0.0f;
    }
}

// Stage C: single block reduces per_class[C] into out[0].
__global__ __launch_bounds__(1024) void finalize_kernel(
    const float* __restrict__ per_class, float* __restrict__ out, int C)
{
    __shared__ float red[1024];
    const int t = threadIdx.x;
    float v = 0.0f;
    for (int c = t; c < C; c += 1024) v += per_class[c];
    red[t] = v;
    __syncthreads();
    #pragma unroll
    for (int s = 512; s > 0; s >>= 1) {
        if (t < s) red[t] += red[t + s];
        __syncthreads();
    }
    if (t == 0) out[0] = red[0];
}

extern "C" void kernel_launch(void* const* d_in, const int* in_sizes, int n_in,
                              void* d_out, int out_size, void* d_ws, size_t ws_size,
                              hipStream_t stream) {
    const float* x       = (const float*)d_in[0];
    const float* anchors = (const float*)d_in[1];
    const int*   y       = (const int*)d_in[2];
    float*       out     = (float*)d_out;

    const int n = in_sizes[2];          // N samples
    const int C = in_sizes[1] / DDIM;   // classes

    // B (streaming blocks) limited by workspace: need B*C*8 + C*4 bytes.
    long long cap = ((long long)ws_size - (long long)C * 4) / ((long long)C * 8);
    int B = (int)(cap < 1 ? 1 : (cap > 2048 ? 2048 : cap));

    float*    pseg      = (float*)d_ws;
    unsigned* pcnt      = (unsigned*)((char*)d_ws + (size_t)B * C * sizeof(float));
    float*    per_class = (float*)((char*)d_ws + (size_t)B * C * 8);

    const size_t ldsBytes = (size_t)C * 8;  // segL + cntL
    dist_kernel<<<B, 256, ldsBytes, stream>>>(x, anchors, y, pseg, pcnt, n, C);
    reduce_kernel<<<C, 256, 0, stream>>>(pseg, pcnt, per_class, B, C);
    finalize_kernel<<<1, 1024, 0, stream>>>(per_class, out, C);
}

// Round 4
// 118.491 us; speedup vs baseline: 3.3947x; 1.0743x over previous
//
#include <hip/hip_runtime.h>

#define DDIM 128

// Stage A: stream x, compute per-sample ||x - a_y||^2 via 16-lane groups
// (2 samples per group per iteration for MLP), accumulate per-class sums/counts
// in LDS, flush per-block partials (no global atomics).  [unchanged from R3]
__global__ __launch_bounds__(256) void dist_kernel(
    const float* __restrict__ x, const float* __restrict__ anchors,
    const int* __restrict__ y,
    float* __restrict__ pseg, unsigned* __restrict__ pcnt,
    int n, int C)
{
    extern __shared__ char smem[];
    float*    segL = (float*)smem;
    unsigned* cntL = (unsigned*)(smem + (size_t)C * sizeof(float));

    for (int c = threadIdx.x; c < C; c += blockDim.x) { segL[c] = 0.0f; cntL[c] = 0u; }
    __syncthreads();

    const int tid  = blockIdx.x * blockDim.x + threadIdx.x;
    const int wave = tid >> 6;
    const int lane = threadIdx.x & 63;
    const int g    = lane >> 4;   // sample group within wave (0..3)
    const int q    = lane & 15;   // lane within 16-lane group
    const int totalWaves = (gridDim.x * blockDim.x) >> 6;
    const int stride = totalWaves * 8;          // 8 samples per wave per iter

    for (int base = wave * 8; base < n; base += stride) {
        const int i0 = base + g;        // sample A for this group
        const int i1 = base + g + 4;    // sample B for this group
        const bool v0 = i0 < n, v1 = i1 < n;

        int l0 = 0, l1 = 0;
        if (v0) l0 = y[i0];
        if (v1) l1 = y[i1];

        float4 xa0, xa1, xb0, xb1;
        float4 aa0, aa1, ab0, ab1;
        if (v0) {
            const float4* xp = (const float4*)(x + (size_t)i0 * DDIM + q * 8);
            xa0 = xp[0]; xa1 = xp[1];
        }
        if (v1) {
            const float4* xp = (const float4*)(x + (size_t)i1 * DDIM + q * 8);
            xb0 = xp[0]; xb1 = xp[1];
        }
        if (v0) {
            const float4* ap = (const float4*)(anchors + (size_t)l0 * DDIM + q * 8);
            aa0 = ap[0]; aa1 = ap[1];
        }
        if (v1) {
            const float4* ap = (const float4*)(anchors + (size_t)l1 * DDIM + q * 8);
            ab0 = ap[0]; ab1 = ap[1];
        }

        float acc0 = 0.0f, acc1 = 0.0f;
        if (v0) {
            float d;
            d = xa0.x - aa0.x; acc0 = fmaf(d, d, acc0);
            d = xa0.y - aa0.y; acc0 = fmaf(d, d, acc0);
            d = xa0.z - aa0.z; acc0 = fmaf(d, d, acc0);
            d = xa0.w - aa0.w; acc0 = fmaf(d, d, acc0);
            d = xa1.x - aa1.x; acc0 = fmaf(d, d, acc0);
            d = xa1.y - aa1.y; acc0 = fmaf(d, d, acc0);
            d = xa1.z - aa1.z; acc0 = fmaf(d, d, acc0);
            d = xa1.w - aa1.w; acc0 = fmaf(d, d, acc0);
        }
        if (v1) {
            float d;
            d = xb0.x - ab0.x; acc1 = fmaf(d, d, acc1);
            d = xb0.y - ab0.y; acc1 = fmaf(d, d, acc1);
            d = xb0.z - ab0.z; acc1 = fmaf(d, d, acc1);
            d = xb0.w - ab0.w; acc1 = fmaf(d, d, acc1);
            d = xb1.x - ab1.x; acc1 = fmaf(d, d, acc1);
            d = xb1.y - ab1.y; acc1 = fmaf(d, d, acc1);
            d = xb1.z - ab1.z; acc1 = fmaf(d, d, acc1);
            d = xb1.w - ab1.w; acc1 = fmaf(d, d, acc1);
        }

        #pragma unroll
        for (int off = 1; off < 16; off <<= 1) {
            acc0 += __shfl_xor(acc0, off);
            acc1 += __shfl_xor(acc1, off);
        }
        if (q == 0) {
            if (v0) { atomicAdd(&segL[l0], acc0); atomicAdd(&cntL[l0], 1u); }
            if (v1) { atomicAdd(&segL[l1], acc1); atomicAdd(&cntL[l1], 1u); }
        }
    }
    __syncthreads();

    float*    myseg = pseg + (size_t)blockIdx.x * C;
    unsigned* mycnt = pcnt + (size_t)blockIdx.x * C;
    for (int c = threadIdx.x; c < C; c += blockDim.x) {
        myseg[c] = segL[c];
        mycnt[c] = cntL[c];
    }
}

// Stage B: 2-D grid (class-chunk, b-slice). Thread t owns class chunk*256+t and
// sums `rowsPerSlice` consecutive partial rows — coalesced reads across threads.
__global__ __launch_bounds__(256) void reduceB_kernel(
    const float* __restrict__ pseg, const unsigned* __restrict__ pcnt,
    float* __restrict__ sseg, float* __restrict__ scnt,
    int B, int C, int rowsPerSlice)
{
    const int c = blockIdx.x * 256 + threadIdx.x;
    if (c >= C) return;
    const int slice = blockIdx.y;
    const int b0 = slice * rowsPerSlice;
    int b1 = b0 + rowsPerSlice; if (b1 > B) b1 = B;

    float s = 0.0f, k = 0.0f;
    #pragma unroll 8
    for (int b = b0; b < b1; ++b) {
        s += pseg[(size_t)b * C + c];
        k += (float)pcnt[(size_t)b * C + c];
    }
    sseg[(size_t)slice * C + c] = s;
    scnt[(size_t)slice * C + c] = k;
}

// Stage C: one block; thread per class sums slice partials (coalesced),
// applies s/k^2, block-reduces to out[0].
__global__ __launch_bounds__(1024) void finalize_kernel(
    const float* __restrict__ sseg, const float* __restrict__ scnt,
    float* __restrict__ out, int nslice, int C)
{
    __shared__ float red[1024];
    const int t = threadIdx.x;
    float v = 0.0f;
    for (int c = t; c < C; c += 1024) {
        float s = 0.0f, k = 0.0f;
        for (int sl = 0; sl < nslice; ++sl) {
            s += sseg[(size_t)sl * C + c];
            k += scnt[(size_t)sl * C + c];
        }
        if (k > 0.0f) v += s / (k * k);
    }
    red[t] = v;
    __syncthreads();
    #pragma unroll
    for (int st = 512; st > 0; st >>= 1) {
        if (t < st) red[t] += red[t + st];
        __syncthreads();
    }
    if (t == 0) out[0] = red[0];
}

extern "C" void kernel_launch(void* const* d_in, const int* in_sizes, int n_in,
                              void* d_out, int out_size, void* d_ws, size_t ws_size,
                              hipStream_t stream) {
    const float* x       = (const float*)d_in[0];
    const float* anchors = (const float*)d_in[1];
    const int*   y       = (const int*)d_in[2];
    float*       out     = (float*)d_out;

    const int n = in_sizes[2];          // N samples
    const int C = in_sizes[1] / DDIM;   // classes

    const int rowsPerSlice = 64;

    // ws layout: pseg[B*C] f32 | pcnt[B*C] u32 | sseg[nslice*C] f32 | scnt[nslice*C] f32
    long long cap = ((long long)ws_size) / ((long long)C * 8 + (long long)C * 16 / rowsPerSlice + 16);
    int B = (int)(cap < 1 ? 1 : (cap > 2048 ? 2048 : cap));
    const int nslice = (B + rowsPerSlice - 1) / rowsPerSlice;

    float*    pseg = (float*)d_ws;
    unsigned* pcnt = (unsigned*)((char*)d_ws + (size_t)B * C * 4);
    float*    sseg = (float*)((char*)d_ws + (size_t)B * C * 8);
    float*    scnt = (float*)((char*)d_ws + (size_t)B * C * 8 + (size_t)nslice * C * 4);

    const size_t ldsBytes = (size_t)C * 8;  // segL + cntL
    dist_kernel<<<B, 256, ldsBytes, stream>>>(x, anchors, y, pseg, pcnt, n, C);

    dim3 gridB((C + 255) / 256, nslice);
    reduceB_kernel<<<gridB, 256, 0, stream>>>(pseg, pcnt, sseg, scnt, B, C, rowsPerSlice);

    finalize_kernel<<<1, 1024, 0, stream>>>(sseg, scnt, out, nslice, C);
}